// Round 17
// baseline (198.378 us; speedup 1.0000x reference)
//
#include <hip/hip_runtime.h>
#include <math.h>

#define BSZ 16
#define NQ 300
#define NT 50
#define K3 51
#define NPRED (BSZ*NQ)     // 4800
#define NTGT  (BSZ*NT)     // 800
#define NC    (NPRED*NTGT) // 3,840,000
#define TSTRIDE 301        // tile row stride (floats)
#define TILEF 15232        // floats per batch tile region
#define SMEMF (2*TILEF)    // 30464 floats = 121856 B -> 1 block/CU everywhere
#define NLAP 8             // 8 LAP blocks x 2 batches each

// DEAD ENDS (do not retry): R2 warm-v infeasible; R4 auction negative; R5 matched-slot
// rescans; R3/R6/R7 inner-loop ALU surgery neutral; R10/R11 fused reg-tile blocked by
// VGPR x occupancy; R12 setprio neutral; R15 exclusive-CU neutral (serial slowness is
// the tile-read chain, not contention); R16 waves_per_eu ignored (VGPR stuck 168) and
// 2-pred cost regressed (occupancy-bound).
// Current: fused, 8 LAP blocks each solving TWO batches with the serial Dijkstra
// 2-way SOFTWARE-INTERLEAVED in wave 0 (B's ticks fill A's LDS-latency stalls);
// per-batch arithmetic = R7-verified f32 SAP, bit-identical trajectories.

// ---------------- DPP wave-min helpers (wave64, all lanes active) ----------------
template<int CTRL, int RMASK>
__device__ __forceinline__ unsigned int dpp_minstep_u32(unsigned int x) {
    unsigned int o = (unsigned int)__builtin_amdgcn_update_dpp((int)x, (int)x, CTRL, RMASK, 0xF, false);
    return (x < o) ? x : o;
}
__device__ __forceinline__ unsigned int wave_min_u32(unsigned int x) {
    x = dpp_minstep_u32<0xB1, 0xF>(x);
    x = dpp_minstep_u32<0x4E, 0xF>(x);
    x = dpp_minstep_u32<0x141, 0xF>(x);
    x = dpp_minstep_u32<0x140, 0xF>(x);
    x = dpp_minstep_u32<0x142, 0xA>(x);
    x = dpp_minstep_u32<0x143, 0xC>(x);
    return (unsigned int)__builtin_amdgcn_readlane((int)x, 63);
}
__device__ __forceinline__ float readlane_f32(float x, int lane) {
    return __int_as_float(__builtin_amdgcn_readlane(__float_as_int(x), lane));
}
__device__ __forceinline__ unsigned int f32key(float x) {
    unsigned int b = (unsigned int)__float_as_int(x);
    return b ^ (((int)b < 0) ? 0xFFFFFFFFu : 0x80000000u);
}

// Identical formula/op-order in both paths.
__device__ __forceinline__ float giou_cost(
    float plt0, float plt1, float plt2, float prb0, float prb1, float prb2, float pvol,
    float tlt0, float tlt1, float tlt2, float trb0, float trb1, float trb2, float tvol)
{
    float inter = fmaxf(fminf(prb0,trb0) - fmaxf(plt0,tlt0), 0.f);
    inter *= fmaxf(fminf(prb1,trb1) - fmaxf(plt1,tlt1), 0.f);
    inter *= fmaxf(fminf(prb2,trb2) - fmaxf(plt2,tlt2), 0.f);
    float evol = fmaxf(fmaxf(prb0,trb0) - fminf(plt0,tlt0), 0.f);
    evol *= fmaxf(fmaxf(prb1,trb1) - fminf(plt1,tlt1), 0.f);
    evol *= fmaxf(fmaxf(prb2,trb2) - fminf(plt2,tlt2), 0.f);
    float uni = pvol + tvol - inter;
    return inter/uni - (evol - uni)/evol;
}

__global__ __launch_bounds__(1024) void fused_kernel(
    const float* __restrict__ pred_kp, const float* __restrict__ pred_boxes,
    const float* __restrict__ tgt_boxes, const float* __restrict__ tgt_kp,
    float* __restrict__ C, float* __restrict__ out_idx)
{
    __shared__ __align__(16) float smem[SMEMF];
    const int bid = blockIdx.x;
    const int tid = threadIdx.x;

    if (bid >= NLAP) {
        // ================= cost-matrix path: 64 preds x 80 tgts (R7-verified) =================
        const int cb = bid - NLAP;
        const int pb = cb % 75, tb = cb / 75;
        const int p0 = pb * 64, t0 = tb * 80;
        float* s_dk   = smem;            // 80 x 56
        float* s_tbox = smem + 4480;     // 80 x 12
        float* s_pk   = smem + 5440;     // 64 x 51

        if (tid < 80) {
            const float* tb6 = tgt_boxes + (size_t)(t0 + tid) * 6;
            float c0=tb6[0], c1=tb6[1], c2=tb6[2], s0=tb6[3], s1=tb6[4], s2=tb6[5];
            float l0=c0-0.5f*s0, l1=c1-0.5f*s1, l2=c2-0.5f*s2;
            float r0=c0+0.5f*s0, r1=c1+0.5f*s1, r2=c2+0.5f*s2;
            float* tw = s_tbox + tid*12;
            tw[0]=l0; tw[1]=l1; tw[2]=l2; tw[3]=r0; tw[4]=r1; tw[5]=r2;
            tw[6]=(r0-l0)*(r1-l1)*(r2-l2);
            tw[9]=s0; tw[10]=s1; tw[11]=s2;
        }
        __syncthreads();
        for (int e = tid; e < 80*K3; e += 1024) {
            int t = e / K3; int c = e - t*K3; int d = c % 3;
            float kp = tgt_kp[(size_t)t0*K3 + e];
            s_dk[t*56 + c] = (kp - s_tbox[t*12 + d]) / s_tbox[t*12 + 9 + d];
        }
        for (int e = tid; e < 64*K3; e += 1024)
            s_pk[e] = pred_kp[(size_t)p0*K3 + e];
        __syncthreads();

        const int pl = tid & 63, g = tid >> 6;
        float a[K3];
        #pragma unroll
        for (int c = 0; c < K3; ++c) a[c] = s_pk[pl*K3 + c];
        const int p = p0 + pl;
        const float* pb6 = pred_boxes + (size_t)p * 6;
        float pc0=pb6[0],pc1=pb6[1],pc2=pb6[2],ps0=pb6[3],ps1=pb6[4],ps2=pb6[5];
        float plt0=pc0-0.5f*ps0, plt1=pc1-0.5f*ps1, plt2=pc2-0.5f*ps2;
        float prb0=pc0+0.5f*ps0, prb1=pc1+0.5f*ps1, prb2=pc2+0.5f*ps2;
        float pvol=(prb0-plt0)*(prb1-plt1)*(prb2-plt2);

        #pragma unroll
        for (int k = 0; k < 5; ++k) {
            int tl = g*5 + k;
            const float* bbp = s_dk + tl*56;
            float sum = 0.f;
            #pragma unroll
            for (int c4 = 0; c4 < 12; ++c4) {
                float4 q = *(const float4*)(bbp + 4*c4);
                sum += fabsf(a[4*c4+0] - q.x);
                sum += fabsf(a[4*c4+1] - q.y);
                sum += fabsf(a[4*c4+2] - q.z);
                sum += fabsf(a[4*c4+3] - q.w);
            }
            sum += fabsf(a[48] - bbp[48]);
            sum += fabsf(a[49] - bbp[49]);
            sum += fabsf(a[50] - bbp[50]);
            const float* tw = s_tbox + tl*12;
            float g_ = giou_cost(plt0,plt1,plt2,prb0,prb1,prb2,pvol,
                                 tw[0],tw[1],tw[2],tw[3],tw[4],tw[5],tw[6]);
            C[(size_t)p*NTGT + (t0+tl)] = sum - g_;
        }
        return;
    }

    // ================= LAP path: one block solves TWO batches =================
    const int ln = tid & 63, w = tid >> 6;

    // ---- build both tiles + rowmin scans (16 waves; R7-verified math) ----
    for (int side = 0; side < 2; ++side) {
        const int bb = 2*bid + side;
        const int bq0 = bb*NQ, bt0 = bb*NT;
        float* tile  = smem + side*TILEF;
        float* s_rmv = tile + 15072;
        int*   s_rmc = (int*)(tile + 15136);

        for (int e = tid; e < NT*K3; e += 1024)
            tile[e] = tgt_kp[(size_t)bt0*K3 + e];
        __syncthreads();

        float dk[K3];
        float tl0=0,tl1=0,tl2=0,tr0=0,tr1=0,tr2=0,tvol=0;
        if (ln < NT) {
            const float* tb6 = tgt_boxes + (size_t)(bt0+ln)*6;
            float c0=tb6[0],c1=tb6[1],c2=tb6[2],s0=tb6[3],s1=tb6[4],s2=tb6[5];
            tl0=c0-0.5f*s0; tl1=c1-0.5f*s1; tl2=c2-0.5f*s2;
            tr0=c0+0.5f*s0; tr1=c1+0.5f*s1; tr2=c2+0.5f*s2;
            tvol=(tr0-tl0)*(tr1-tl1)*(tr2-tl2);
            #pragma unroll
            for (int c = 0; c < K3; ++c) {
                int d = c % 3;
                float L = (d==0)?tl0:((d==1)?tl1:tl2);
                float S = (d==0)?s0:((d==1)?s1:s2);
                dk[c] = (tile[ln*K3 + c] - L) / S;
            }
        }
        __syncthreads();

        for (int p = w; p < NQ; p += 16) {
            const float* prow = pred_kp + (size_t)(bq0+p)*K3;
            const float* pb6  = pred_boxes + (size_t)(bq0+p)*6;
            float pc0=pb6[0],pc1=pb6[1],pc2=pb6[2],ps0=pb6[3],ps1=pb6[4],ps2=pb6[5];
            float plt0=pc0-0.5f*ps0, plt1=pc1-0.5f*ps1, plt2=pc2-0.5f*ps2;
            float prb0=pc0+0.5f*ps0, prb1=pc1+0.5f*ps1, prb2=pc2+0.5f*ps2;
            float pvol=(prb0-plt0)*(prb1-plt1)*(prb2-plt2);
            if (ln < NT) {
                float sum = 0.f;
                #pragma unroll
                for (int c = 0; c < K3; ++c) sum += fabsf(prow[c] - dk[c]);
                float g_ = giou_cost(plt0,plt1,plt2,prb0,prb1,prb2,pvol,
                                     tl0,tl1,tl2,tr0,tr1,tr2,tvol);
                tile[ln*TSTRIDE + p] = sum - g_;
            }
        }
        __syncthreads();

        for (int r = w; r < NT; r += 16) {
            float bv = __builtin_inff(); int bj = 0x7fffffff;
            #pragma unroll
            for (int s = 0; s < 5; ++s) {
                int j = ln + 64*s;
                if (j < NQ) {
                    float cv = tile[r*TSTRIDE + j];
                    if (cv < bv || (cv == bv && j < bj)) { bv = cv; bj = j; }
                }
            }
            #pragma unroll
            for (int off = 32; off > 0; off >>= 1) {
                float ov = __shfl_xor(bv, off);
                int   oj = __shfl_xor(bj, off);
                if (ov < bv || (ov == bv && oj < bj)) { bv = ov; bj = oj; }
            }
            if (ln == 0) { s_rmv[r] = bv; s_rmc[r] = bj; }
        }
        __syncthreads();
    }
    if (w != 0) return;                 // wave 0 continues alone

    float* tileA = smem;          float* tileB = smem + TILEF;
    float* rmvA  = tileA + 15072; float* rmvB  = tileB + 15072;
    int*   rmcA  = (int*)(tileA + 15136); int* rmcB = (int*)(tileB + 15136);
    const float FINF = __builtin_inff();

    // ---- greedy init (R7-verified), per side ----
    float uA = 0.f; int c4rA = -1;
    if (ln < NT) uA = rmvA[ln];
    { int wantj = (ln < NT) ? rmcA[ln] : -1;
      for (int r = 0; r < NT; ++r) {
          int j = __builtin_amdgcn_readlane(wantj, r);
          unsigned long long tk = __ballot((ln < NT) && (c4rA == j));
          if (tk == 0ull && ln == r) c4rA = j;
      } }
    float uB = 0.f; int c4rB = -1;
    if (ln < NT) uB = rmvB[ln];
    { int wantj = (ln < NT) ? rmcB[ln] : -1;
      for (int r = 0; r < NT; ++r) {
          int j = __builtin_amdgcn_readlane(wantj, r);
          unsigned long long tk = __ballot((ln < NT) && (c4rB == j));
          if (tk == 0ull && ln == r) c4rB = j;
      } }

    float vA[5], vB[5], shA[5], shB[5];
    int pthA[5], pthB[5];
    #pragma unroll
    for (int s = 0; s < 5; ++s) { vA[s] = 0.f; vB[s] = 0.f; }

    int crA = 0, crB = 0, iA = 0, iB = 0, sinkA = -1, sinkB = -1;
    int SCmA = 0, SCmB = 0;
    unsigned long long SRA = 0ull, SRB = 0ull;
    float mvA = 0.f, mvB = 0.f;
    bool actA = false, actB = false, doneA = false, doneB = false;

    // ---- interleaved dual-batch SAP: tickA and tickB per loop (uniform control) ----
    for (int tick = 0; tick < 4096; ++tick) {
        if (!actA && !doneA) {
            while (crA < NT && __builtin_amdgcn_readlane(c4rA, crA) >= 0) ++crA;
            if (crA >= NT) doneA = true;
            else {
                #pragma unroll
                for (int s = 0; s < 5; ++s) { shA[s] = FINF; pthA[s] = -1; }
                SCmA = (ln < 60) ? 0 : 0x1F; SRA = 0ull; iA = crA; mvA = 0.f; sinkA = -1; actA = true;
            }
        }
        if (!actB && !doneB) {
            while (crB < NT && __builtin_amdgcn_readlane(c4rB, crB) >= 0) ++crB;
            if (crB >= NT) doneB = true;
            else {
                #pragma unroll
                for (int s = 0; s < 5; ++s) { shB[s] = FINF; pthB[s] = -1; }
                SCmB = (ln < 60) ? 0 : 0x1F; SRB = 0ull; iB = crB; mvB = 0.f; sinkB = -1; actB = true;
            }
        }
        if (doneA && doneB) break;

        // hoist both rows' LDS loads (latencies overlap)
        float cfA[5] = {0,0,0,0,0}, cfB[5] = {0,0,0,0,0};
        if (actA && ln < 60) {
            const float* rp = tileA + iA*TSTRIDE + 5*ln;
            cfA[0]=rp[0]; cfA[1]=rp[1]; cfA[2]=rp[2]; cfA[3]=rp[3]; cfA[4]=rp[4];
        }
        if (actB && ln < 60) {
            const float* rp = tileB + iB*TSTRIDE + 5*ln;
            cfB[0]=rp[0]; cfB[1]=rp[1]; cfB[2]=rp[2]; cfB[3]=rp[3]; cfB[4]=rp[4];
        }

        bool finA = false, finB = false;
        if (actA) {
            SRA |= 1ull << iA;
            float u_i = readlane_f32(uA, iA);
            float e[5];
            #pragma unroll
            for (int s = 0; s < 5; ++s) {
                bool open = ((SCmA >> s) & 1) == 0;
                float r = ((mvA + cfA[s]) - u_i) - vA[s];
                bool upd = open && (r < shA[s]);
                shA[s]  = upd ? r : shA[s];
                pthA[s] = upd ? iA : pthA[s];
                e[s] = open ? shA[s] : FINF;
            }
            float lmin = fminf(fminf(fminf(e[0], e[1]), fminf(e[2], e[3])), e[4]);
            int aslot = (e[0]==lmin) ? 0 : (e[1]==lmin) ? 1 :
                        (e[2]==lmin) ? 2 : (e[3]==lmin) ? 3 : 4;
            unsigned int kmin = wave_min_u32(f32key(lmin));
            unsigned long long cands = __ballot(f32key(lmin) == kmin);
            int lstar = __builtin_ctzll(cands);
            float m = readlane_f32(lmin, lstar);
            int jstar = 5*lstar + __builtin_amdgcn_readlane(aslot, lstar);
            mvA = m;
            unsigned long long mm = __ballot((ln < NT) && (c4rA == jstar));
            if (ln == lstar) SCmA |= 1 << (jstar - 5*lstar);
            if (mm == 0ull) { sinkA = jstar; actA = false; finA = true; }
            else iA = __builtin_ctzll(mm);
        }
        if (actB) {
            SRB |= 1ull << iB;
            float u_i = readlane_f32(uB, iB);
            float e[5];
            #pragma unroll
            for (int s = 0; s < 5; ++s) {
                bool open = ((SCmB >> s) & 1) == 0;
                float r = ((mvB + cfB[s]) - u_i) - vB[s];
                bool upd = open && (r < shB[s]);
                shB[s]  = upd ? r : shB[s];
                pthB[s] = upd ? iB : pthB[s];
                e[s] = open ? shB[s] : FINF;
            }
            float lmin = fminf(fminf(fminf(e[0], e[1]), fminf(e[2], e[3])), e[4]);
            int aslot = (e[0]==lmin) ? 0 : (e[1]==lmin) ? 1 :
                        (e[2]==lmin) ? 2 : (e[3]==lmin) ? 3 : 4;
            unsigned int kmin = wave_min_u32(f32key(lmin));
            unsigned long long cands = __ballot(f32key(lmin) == kmin);
            int lstar = __builtin_ctzll(cands);
            float m = readlane_f32(lmin, lstar);
            int jstar = 5*lstar + __builtin_amdgcn_readlane(aslot, lstar);
            mvB = m;
            unsigned long long mm = __ballot((ln < NT) && (c4rB == jstar));
            if (ln == lstar) SCmB |= 1 << (jstar - 5*lstar);
            if (mm == 0ull) { sinkB = jstar; actB = false; finB = true; }
            else iB = __builtin_ctzll(mm);
        }

        if (finA) {      // dual update + augment A (R7 verbatim, curRow = crA)
            int cg  = (c4rA >= 0) ? c4rA : 0;
            int gow = cg / 5, gsl = cg - 5*gow;
            float g0 = __shfl(shA[0], gow), g1 = __shfl(shA[1], gow);
            float g2 = __shfl(shA[2], gow), g3 = __shfl(shA[3], gow);
            float g4 = __shfl(shA[4], gow);
            float gg = g0;
            gg = (gsl == 1) ? g1 : gg; gg = (gsl == 2) ? g2 : gg;
            gg = (gsl == 3) ? g3 : gg; gg = (gsl == 4) ? g4 : gg;
            bool inSR = (ln < NT) && ((SRA >> ln) & 1ull);
            float du = (ln == crA) ? mvA : (mvA - gg);
            uA = inSR ? (uA + du) : uA;
            #pragma unroll
            for (int s = 0; s < 5; ++s) {
                bool closed = ((SCmA >> s) & 1) != 0;
                vA[s] = closed ? (vA[s] - (mvA - shA[s])) : vA[s];
            }
            int j = sinkA;
            for (int g2_ = 0; g2_ < 64; ++g2_) {
                int ow2 = j / 5, sl2 = j - 5*ow2;
                int ps = pthA[0];
                ps = (sl2==1) ? pthA[1] : ps; ps = (sl2==2) ? pthA[2] : ps;
                ps = (sl2==3) ? pthA[3] : ps; ps = (sl2==4) ? pthA[4] : ps;
                int ii = __builtin_amdgcn_readlane(ps, ow2);
                int jj = __builtin_amdgcn_readlane(c4rA, ii);
                if (ln == ii) c4rA = j;
                j = jj;
                if (ii == crA) break;
            }
        }
        if (finB) {      // dual update + augment B
            int cg  = (c4rB >= 0) ? c4rB : 0;
            int gow = cg / 5, gsl = cg - 5*gow;
            float g0 = __shfl(shB[0], gow), g1 = __shfl(shB[1], gow);
            float g2 = __shfl(shB[2], gow), g3 = __shfl(shB[3], gow);
            float g4 = __shfl(shB[4], gow);
            float gg = g0;
            gg = (gsl == 1) ? g1 : gg; gg = (gsl == 2) ? g2 : gg;
            gg = (gsl == 3) ? g3 : gg; gg = (gsl == 4) ? g4 : gg;
            bool inSR = (ln < NT) && ((SRB >> ln) & 1ull);
            float du = (ln == crB) ? mvB : (mvB - gg);
            uB = inSR ? (uB + du) : uB;
            #pragma unroll
            for (int s = 0; s < 5; ++s) {
                bool closed = ((SCmB >> s) & 1) != 0;
                vB[s] = closed ? (vB[s] - (mvB - shB[s])) : vB[s];
            }
            int j = sinkB;
            for (int g2_ = 0; g2_ < 64; ++g2_) {
                int ow2 = j / 5, sl2 = j - 5*ow2;
                int ps = pthB[0];
                ps = (sl2==1) ? pthB[1] : ps; ps = (sl2==2) ? pthB[2] : ps;
                ps = (sl2==3) ? pthB[3] : ps; ps = (sl2==4) ? pthB[4] : ps;
                int ii = __builtin_amdgcn_readlane(ps, ow2);
                int jj = __builtin_amdgcn_readlane(c4rB, ii);
                if (ln == ii) c4rB = j;
                j = jj;
                if (ii == crB) break;
            }
        }
    }

    // ---- emit indices for both batches ----
    {
        int* smem_i = (int*)tileA;
        __threadfence_block();
        if (ln < NT) smem_i[ln] = c4rA;
        __threadfence_block();
        int myc = c4rA, rank = 0;
        for (int s2 = 0; s2 < NT; ++s2) rank += (smem_i[s2] < myc) ? 1 : 0;
        const int bA = 2*bid;
        if (ln < NT) {
            out_idx[bA*(2*NT) + rank]      = (float)myc;
            out_idx[bA*(2*NT) + NT + rank] = (float)ln;
        }
    }
    {
        int* smem_i = (int*)tileB;
        __threadfence_block();
        if (ln < NT) smem_i[ln] = c4rB;
        __threadfence_block();
        int myc = c4rB, rank = 0;
        for (int s2 = 0; s2 < NT; ++s2) rank += (smem_i[s2] < myc) ? 1 : 0;
        const int bB = 2*bid + 1;
        if (ln < NT) {
            out_idx[bB*(2*NT) + rank]      = (float)myc;
            out_idx[bB*(2*NT) + NT + rank] = (float)ln;
        }
    }
}

extern "C" void kernel_launch(void* const* d_in, const int* in_sizes, int n_in,
                              void* d_out, int out_size, void* d_ws, size_t ws_size,
                              hipStream_t stream)
{
    const float* pred_kp    = (const float*)d_in[0];
    const float* pred_boxes = (const float*)d_in[1];
    const float* tgt_boxes  = (const float*)d_in[2];
    const float* tgt_kp     = (const float*)d_in[3];
    float* C   = (float*)d_out;
    float* idx = C + NC;
    // blocks 0..7: dual-batch LAP (dispatched first); blocks 8..757: cost matrix
    fused_kernel<<<dim3(NLAP + 750), 1024, 0, stream>>>(
        pred_kp, pred_boxes, tgt_boxes, tgt_kp, C, idx);
}